// Round 2
// baseline (427.613 us; speedup 1.0000x reference)
//
#include <hip/hip_runtime.h>
#include <hip/hip_bf16.h>

// SelfAttention_592705487560 — N=4096, D=128, H=8
// scores = V·Q^T (flash roles: query=v, key=q, value=k), softmax over q-index.
// Score path (q,v) uses double-bf16 (hi+lo) 3-term MFMA for f32-like accuracy;
// k path / P / out-proj are plain bf16 MFMA (error contribution ~0.04 abs).
// ws (bf16 elems): xh,xl 512K ea | WTh,WTl 384K ea | WoT 128K |
//                  Qh,Ql,Vh,Vl,Kt,OUTS 4M ea  => ~54.3 MB

typedef __attribute__((ext_vector_type(8))) short short8;   // 8 x bf16 (4 VGPRs)
typedef __attribute__((ext_vector_type(4))) float f32x4;

#define MFMA(a,b,c) __builtin_amdgcn_mfma_f32_16x16x32_bf16((a),(b),(c),0,0,0)
#define LOG2E 1.44269504088896340736f

static __device__ __forceinline__ unsigned short f2bf(float f) {
  union { float f; unsigned u; } v; v.f = f;
  unsigned r = v.u + 0x7fffu + ((v.u >> 16) & 1u);   // round-to-nearest-even
  return (unsigned short)(r >> 16);
}
static __device__ __forceinline__ float bf2f(unsigned short h) {
  union { unsigned u; float f; } v; v.u = ((unsigned)h) << 16; return v.f;
}
static __device__ __forceinline__ void split2(float f, unsigned short& hi, unsigned short& lo) {
  hi = f2bf(f);
  lo = f2bf(f - bf2f(hi));
}

// ---------------- prep 1: x f32 -> bf16 hi/lo ----------------
__global__ __launch_bounds__(256) void kxbf(const float* __restrict__ x,
                                            unsigned short* __restrict__ xh,
                                            unsigned short* __restrict__ xl) {
  int i = blockIdx.x * 256 + threadIdx.x;      // 131072 float4s, grid=512
  float4 v = reinterpret_cast<const float4*>(x)[i];
  ushort4 oh, ol;
  split2(v.x, oh.x, ol.x); split2(v.y, oh.y, ol.y);
  split2(v.z, oh.z, ol.z); split2(v.w, oh.w, ol.w);
  reinterpret_cast<ushort4*>(xh)[i] = oh;
  reinterpret_cast<ushort4*>(xl)[i] = ol;
}

// ---------------- prep 2: transpose weights to bf16 hi/lo ----------------
// blocks 0..23: WTh/WTl[slot][h][e][d] = W[slot][h][d][e]  (slot 0=Wq,1=Wk,2=Wv)
// blocks 24..31: WoT[e][bb*128+k] = Wo[bb*128+k][e]  (hi only)
__global__ __launch_bounds__(256) void kwt(const float* __restrict__ Wq,
                                           const float* __restrict__ Wk,
                                           const float* __restrict__ Wv,
                                           const float* __restrict__ Wo,
                                           unsigned short* __restrict__ WTh,
                                           unsigned short* __restrict__ WTl,
                                           unsigned short* __restrict__ WoT) {
  __shared__ float lds[64 * 130];
  int b = blockIdx.x, t = threadIdx.x;
  const float* src; int isWo;
  if (b < 24) {
    int slot = b >> 3, hh = b & 7;
    src = (slot == 0 ? Wq : (slot == 1 ? Wk : Wv)) + hh * 16384;
    isWo = 0;
  } else {
    src = Wo + (b - 24) * 16384;
    isWo = 1;
  }
  for (int half = 0; half < 2; ++half) {
#pragma unroll
    for (int i = 0; i < 8; ++i) {              // stage 64 rows x 128 cols f32
      int lin = i * 1024 + t * 4;
      int row = lin >> 7, col = lin & 127;
      float4 v = *reinterpret_cast<const float4*>(src + half * 8192 + lin);
      lds[row * 130 + col + 0] = v.x;
      lds[row * 130 + col + 1] = v.y;
      lds[row * 130 + col + 2] = v.z;
      lds[row * 130 + col + 3] = v.w;
    }
    __syncthreads();
    int e = t >> 1, k0 = (t & 1) * 32;
    float buf[32];
#pragma unroll
    for (int j = 0; j < 32; ++j) buf[j] = lds[(k0 + j) * 130 + e];
    int kg = half * 64 + k0;
    if (!isWo) {
      unsigned short* dh = WTh + b * 16384 + e * 128 + kg;
      unsigned short* dl = WTl + b * 16384 + e * 128 + kg;
#pragma unroll
      for (int c = 0; c < 4; ++c) {
        short8 oh, ol;
#pragma unroll
        for (int jj = 0; jj < 8; ++jj) {
          unsigned short h, l; split2(buf[c * 8 + jj], h, l);
          oh[jj] = (short)h; ol[jj] = (short)l;
        }
        *reinterpret_cast<short8*>(dh + c * 8) = oh;
        *reinterpret_cast<short8*>(dl + c * 8) = ol;
      }
    } else {
      unsigned short* dst = WoT + e * 1024 + (b - 24) * 128 + kg;
#pragma unroll
      for (int c = 0; c < 4; ++c) {
        short8 o;
#pragma unroll
        for (int jj = 0; jj < 8; ++jj) o[jj] = (short)f2bf(buf[c * 8 + jj]);
        *reinterpret_cast<short8*>(dst + c * 8) = o;
      }
    }
    __syncthreads();
  }
}

// ---------------- projections ----------------
// z=0 -> Qh/Ql[h][n][e] (3-term), z=1 -> Vh/Vl[h][n][e] (3-term),
// z=2 -> Kt[h][e][n] (plain, transposed via LDS)
__global__ __launch_bounds__(256) void kproj(const unsigned short* __restrict__ xh,
                                             const unsigned short* __restrict__ xl,
                                             const unsigned short* __restrict__ WThg,
                                             const unsigned short* __restrict__ WTlg,
                                             const float* __restrict__ bq,
                                             const float* __restrict__ bk,
                                             const float* __restrict__ bv,
                                             unsigned short* __restrict__ Qh,
                                             unsigned short* __restrict__ Ql,
                                             unsigned short* __restrict__ Vh,
                                             unsigned short* __restrict__ Vl,
                                             unsigned short* __restrict__ Kt) {
  __shared__ __align__(16) unsigned char lds[64 * 128 * 2];
  int nb = blockIdx.x, h = blockIdx.y, z = blockIdx.z;
  int t = threadIdx.x, lane = t & 63, w = t >> 6;
  int r = lane & 15, g = lane >> 4;
  int slot = (z == 0) ? 0 : (z == 1 ? 2 : 1);
  const unsigned short* Wth = WThg + (slot * 8 + h) * 16384;   // [e][d]
  const unsigned short* Wtl = WTlg + (slot * 8 + h) * 16384;
  const float* bias = (z == 0) ? bq : (z == 1 ? bv : bk);
  int rowbase = nb * 64 + w * 16;

  short8 ah[4], al[4];
#pragma unroll
  for (int kc = 0; kc < 4; ++kc) {
    ah[kc] = *reinterpret_cast<const short8*>(xh + (rowbase + r) * 128 + kc * 32 + g * 8);
    al[kc] = *reinterpret_cast<const short8*>(xl + (rowbase + r) * 128 + kc * 32 + g * 8);
  }
  f32x4 acc[8];
#pragma unroll
  for (int ct = 0; ct < 8; ++ct) acc[ct] = (f32x4){0.f, 0.f, 0.f, 0.f};
  if (z < 2) {
#pragma unroll
    for (int ct = 0; ct < 8; ++ct) {
#pragma unroll
      for (int kc = 0; kc < 4; ++kc) {
        short8 bh = *reinterpret_cast<const short8*>(Wth + (ct * 16 + r) * 128 + kc * 32 + g * 8);
        short8 bl = *reinterpret_cast<const short8*>(Wtl + (ct * 16 + r) * 128 + kc * 32 + g * 8);
        acc[ct] = MFMA(ah[kc], bh, acc[ct]);
        acc[ct] = MFMA(ah[kc], bl, acc[ct]);
        acc[ct] = MFMA(al[kc], bh, acc[ct]);
      }
    }
    unsigned short* dh = ((z == 0) ? Qh : Vh) + (size_t)h * 4096 * 128;
    unsigned short* dl = ((z == 0) ? Ql : Vl) + (size_t)h * 4096 * 128;
#pragma unroll
    for (int ct = 0; ct < 8; ++ct) {
      int e = ct * 16 + r;
      float bb = bias[h * 128 + e];
#pragma unroll
      for (int rr = 0; rr < 4; ++rr) {
        int n = rowbase + g * 4 + rr;
        unsigned short vh_, vl_; split2(acc[ct][rr] + bb, vh_, vl_);
        dh[n * 128 + e] = vh_;
        dl[n * 128 + e] = vl_;
      }
    }
  } else {
#pragma unroll
    for (int ct = 0; ct < 8; ++ct) {
#pragma unroll
      for (int kc = 0; kc < 4; ++kc) {
        short8 bh = *reinterpret_cast<const short8*>(Wth + (ct * 16 + r) * 128 + kc * 32 + g * 8);
        acc[ct] = MFMA(ah[kc], bh, acc[ct]);
      }
    }
    // write C into swizzled LDS, then stream out transposed as Kt[h][e][n]
#pragma unroll
    for (int ct = 0; ct < 8; ++ct) {
      int e = ct * 16 + r;
      float bb = bias[h * 128 + e];
#pragma unroll
      for (int rr = 0; rr < 4; ++rr) {
        int n = w * 16 + g * 4 + rr;
        unsigned off = ((unsigned)(n * 128 + e) * 2u) ^ ((unsigned)(n & 7) << 4);
        *reinterpret_cast<unsigned short*>(lds + off) = f2bf(acc[ct][rr] + bb);
      }
    }
    __syncthreads();
    int e = t >> 1, n0 = (t & 1) * 32;
    unsigned short buf[32];
#pragma unroll
    for (int j = 0; j < 32; ++j) {
      int n = n0 + j;
      unsigned off = ((unsigned)(n * 128 + e) * 2u) ^ ((unsigned)(n & 7) << 4);
      buf[j] = *reinterpret_cast<unsigned short*>(lds + off);
    }
    unsigned short* dst = Kt + ((size_t)h * 128 + e) * 4096 + nb * 64 + n0;
#pragma unroll
    for (int c = 0; c < 4; ++c) {
      short8 o;
#pragma unroll
      for (int jj = 0; jj < 8; ++jj) o[jj] = (short)buf[c * 8 + jj];
      *reinterpret_cast<short8*>(dst + c * 8) = o;
    }
  }
}

// ---------------- flash attention (query=V, key=Q, value=K) ----------------
// grid (64 n-blocks, 8 heads), 4 waves x 16 V-rows. OUTS[n][h*128+d] bf16.
// Scores in double-bf16: s = vh*qh + vh*ql + vl*qh.
__global__ __launch_bounds__(256) void kattn(const unsigned short* __restrict__ Qh,
                                             const unsigned short* __restrict__ Ql,
                                             const unsigned short* __restrict__ Kt,
                                             const unsigned short* __restrict__ Vh,
                                             const unsigned short* __restrict__ Vl,
                                             unsigned short* __restrict__ OUTS) {
  __shared__ __align__(16) unsigned char qldsh[64 * 128 * 2];  // [m][d] swizzled
  __shared__ __align__(16) unsigned char qldsl[64 * 128 * 2];  // [m][d] swizzled
  __shared__ __align__(16) unsigned char klds[128 * 64 * 2];   // [d][m] swizzled
  __shared__ __align__(16) unsigned short plds[4][16 * 40];    // per-wave P, stride 40
  int nb = blockIdx.x, h = blockIdx.y;
  int t = threadIdx.x, lane = t & 63, w = t >> 6;
  int r = lane & 15, g = lane >> 4;
  const unsigned short* Qhh = Qh + (size_t)h * 4096 * 128;
  const unsigned short* Qlh = Ql + (size_t)h * 4096 * 128;
  const unsigned short* Kh  = Kt + (size_t)h * 128 * 4096;
  const unsigned short* Vhh = Vh + (size_t)h * 4096 * 128;
  const unsigned short* Vlh = Vl + (size_t)h * 4096 * 128;

  int vrow = nb * 64 + w * 16 + r;
  short8 vah[4], val[4];
#pragma unroll
  for (int kc = 0; kc < 4; ++kc) {
    vah[kc] = *reinterpret_cast<const short8*>(Vhh + (size_t)vrow * 128 + kc * 32 + g * 8);
    val[kc] = *reinterpret_cast<const short8*>(Vlh + (size_t)vrow * 128 + kc * 32 + g * 8);
  }

  f32x4 oacc[8];
#pragma unroll
  for (int dt = 0; dt < 8; ++dt) oacc[dt] = (f32x4){0.f, 0.f, 0.f, 0.f};
  float mrun[4] = {-3e38f, -3e38f, -3e38f, -3e38f};
  float lrun[4] = {0.f, 0.f, 0.f, 0.f};

  int qsm = t >> 4, qsd = (t & 15) * 8;     // Q staging map
  int ksd = t >> 3, ksm = (t & 7) * 8;      // K staging map

  for (int mt = 0; mt < 64; ++mt) {
    int mbase = mt * 64;
#pragma unroll
    for (int i = 0; i < 4; ++i) {           // stage Qh,Ql tiles [64][128]
      int mm = qsm + i * 16;
      unsigned off = ((unsigned)(mm * 128 + qsd) * 2u) ^ ((unsigned)(mm & 7) << 4);
      short8 v0 = *reinterpret_cast<const short8*>(Qhh + (size_t)(mbase + mm) * 128 + qsd);
      short8 v1 = *reinterpret_cast<const short8*>(Qlh + (size_t)(mbase + mm) * 128 + qsd);
      *reinterpret_cast<short8*>(qldsh + off) = v0;
      *reinterpret_cast<short8*>(qldsl + off) = v1;
    }
#pragma unroll
    for (int i = 0; i < 4; ++i) {           // stage K^T tile [128][64]
      int d = ksd + i * 32;
      short8 v = *reinterpret_cast<const short8*>(Kh + (size_t)d * 4096 + mbase + ksm);
      unsigned off = ((unsigned)(d * 64 + ksm) * 2u) ^ ((unsigned)(d & 7) << 4);
      *reinterpret_cast<short8*>(klds + off) = v;
    }
    __syncthreads();
#pragma unroll
    for (int c2 = 0; c2 < 2; ++c2) {        // two 32-wide m-chunks
      int mo = c2 * 32;
      f32x4 s0 = (f32x4){0.f, 0.f, 0.f, 0.f};
      f32x4 s1 = (f32x4){0.f, 0.f, 0.f, 0.f};
#pragma unroll
      for (int kc = 0; kc < 4; ++kc) {
        int dof = kc * 32 + g * 8;
        int m0 = mo + r, m1 = mo + 16 + r;
        unsigned o0 = ((unsigned)(m0 * 128 + dof) * 2u) ^ ((unsigned)(m0 & 7) << 4);
        unsigned o1 = ((unsigned)(m1 * 128 + dof) * 2u) ^ ((unsigned)(m1 & 7) << 4);
        short8 qh0 = *reinterpret_cast<const short8*>(qldsh + o0);
        short8 qh1 = *reinterpret_cast<const short8*>(qldsh + o1);
        short8 ql0 = *reinterpret_cast<const short8*>(qldsl + o0);
        short8 ql1 = *reinterpret_cast<const short8*>(qldsl + o1);
        s0 = MFMA(vah[kc], qh0, s0);
        s1 = MFMA(vah[kc], qh1, s1);
        s0 = MFMA(vah[kc], ql0, s0);
        s1 = MFMA(vah[kc], ql1, s1);
        s0 = MFMA(val[kc], qh0, s0);
        s1 = MFMA(val[kc], qh1, s1);
      }
      // ---- online softmax over this chunk's 32 columns ----
      float mx[4], p0[4], p1[4], sc[4], ps[4];
#pragma unroll
      for (int rr = 0; rr < 4; ++rr) mx[rr] = fmaxf(s0[rr], s1[rr]);
#pragma unroll
      for (int o = 1; o < 16; o <<= 1) {
#pragma unroll
        for (int rr = 0; rr < 4; ++rr) mx[rr] = fmaxf(mx[rr], __shfl_xor(mx[rr], o));
      }
#pragma unroll
      for (int rr = 0; rr < 4; ++rr) {
        float nm = fmaxf(mrun[rr], mx[rr]);
        sc[rr] = exp2f((mrun[rr] - nm) * LOG2E);
        mrun[rr] = nm;
        p0[rr] = exp2f((s0[rr] - nm) * LOG2E);
        p1[rr] = exp2f((s1[rr] - nm) * LOG2E);
        ps[rr] = p0[rr] + p1[rr];
      }
#pragma unroll
      for (int o = 1; o < 16; o <<= 1) {
#pragma unroll
        for (int rr = 0; rr < 4; ++rr) ps[rr] += __shfl_xor(ps[rr], o);
      }
#pragma unroll
      for (int rr = 0; rr < 4; ++rr) lrun[rr] = lrun[rr] * sc[rr] + ps[rr];
#pragma unroll
      for (int dt = 0; dt < 8; ++dt) {
#pragma unroll
        for (int rr = 0; rr < 4; ++rr) oacc[dt][rr] *= sc[rr];
      }
      // P -> LDS (C-layout scatter) -> A-fragment
#pragma unroll
      for (int rr = 0; rr < 4; ++rr) {
        int row = g * 4 + rr;
        plds[w][row * 40 + r]      = f2bf(p0[rr]);
        plds[w][row * 40 + 16 + r] = f2bf(p1[rr]);
      }
      short8 pa = *reinterpret_cast<const short8*>(&plds[w][r * 40 + g * 8]);
#pragma unroll
      for (int dt = 0; dt < 8; ++dt) {      // O += P @ K
        int d = dt * 16 + r;
        short8 kb = *reinterpret_cast<const short8*>(
            klds + (((unsigned)(d * 64 + mo + g * 8) * 2u) ^ ((unsigned)(d & 7) << 4)));
        oacc[dt] = MFMA(pa, kb, oacc[dt]);
      }
    }
    __syncthreads();
  }
  // epilogue: normalize, write OUTS[n][h*128+d]
#pragma unroll
  for (int dt = 0; dt < 8; ++dt) {
#pragma unroll
    for (int rr = 0; rr < 4; ++rr) {
      int n = nb * 64 + w * 16 + g * 4 + rr;
      OUTS[(size_t)n * 1024 + h * 128 + dt * 16 + r] = f2bf(oacc[dt][rr] / lrun[rr]);
    }
  }
}

// ---------------- output projection ----------------
__global__ __launch_bounds__(256) void kout(const unsigned short* __restrict__ OUTS,
                                            const unsigned short* __restrict__ WoT,
                                            const float* __restrict__ bo,
                                            float* __restrict__ out) {
  int rb = blockIdx.x, ch = blockIdx.y;
  int t = threadIdx.x, lane = t & 63, w = t >> 6;
  int r = lane & 15, g = lane >> 4;
  int row = rb * 16 + r;
  int e0 = ch * 64 + w * 16;
  f32x4 acc = (f32x4){0.f, 0.f, 0.f, 0.f};
#pragma unroll
  for (int kc = 0; kc < 32; ++kc) {
    short8 a = *reinterpret_cast<const short8*>(OUTS + (size_t)row * 1024 + kc * 32 + g * 8);
    short8 b = *reinterpret_cast<const short8*>(WoT + (size_t)(e0 + r) * 1024 + kc * 32 + g * 8);
    acc = MFMA(a, b, acc);
  }
  float bov = bo[e0 + r];
#pragma unroll
  for (int rr = 0; rr < 4; ++rr) {
    int n = rb * 16 + g * 4 + rr;
    out[(size_t)n * 128 + e0 + r] = acc[rr] + bov;
  }
}

extern "C" void kernel_launch(void* const* d_in, const int* in_sizes, int n_in,
                              void* d_out, int out_size, void* d_ws, size_t ws_size,
                              hipStream_t stream) {
  const float* x  = (const float*)d_in[0];
  const float* Wq = (const float*)d_in[1];
  const float* bq = (const float*)d_in[2];
  const float* Wk = (const float*)d_in[3];
  const float* bk = (const float*)d_in[4];
  const float* Wv = (const float*)d_in[5];
  const float* bv = (const float*)d_in[6];
  const float* Wo = (const float*)d_in[7];
  const float* bo = (const float*)d_in[8];
  float* out = (float*)d_out;

  unsigned short* ws = (unsigned short*)d_ws;   // needs ~54.3 MB
  unsigned short* xh   = ws;                    // 524288
  unsigned short* xl   = xh + 524288;           // 524288
  unsigned short* WTh  = xl + 524288;           // 393216
  unsigned short* WTl  = WTh + 393216;          // 393216
  unsigned short* WoT  = WTl + 393216;          // 131072
  unsigned short* Qh   = WoT + 131072;          // 4194304
  unsigned short* Ql   = Qh + 4194304;          // 4194304
  unsigned short* Vh   = Ql + 4194304;          // 4194304
  unsigned short* Vl   = Vh + 4194304;          // 4194304
  unsigned short* Kt   = Vl + 4194304;          // 4194304
  unsigned short* OUTS = Kt + 4194304;          // 4194304

  kxbf<<<512, 256, 0, stream>>>(x, xh, xl);
  kwt<<<32, 256, 0, stream>>>(Wq, Wk, Wv, Wo, WTh, WTl, WoT);
  kproj<<<dim3(64, 8, 3), 256, 0, stream>>>(xh, xl, WTh, WTl, bq, bk, bv,
                                            Qh, Ql, Vh, Vl, Kt);
  kattn<<<dim3(64, 8), 256, 0, stream>>>(Qh, Ql, Kt, Vh, Vl, OUTS);
  kout<<<dim3(256, 2), 256, 0, stream>>>(OUTS, WoT, bo, out);
}

// Round 3
// 285.402 us; speedup vs baseline: 1.4983x; 1.4983x over previous
//
#include <hip/hip_runtime.h>
#include <hip/hip_bf16.h>

// SelfAttention_592705487560 — N=4096, D=128, H=8
// scores = V·Q^T (flash roles: query=v, key=q, value=k), softmax over q-index.
// Round 3: swapped-operand scores C[m][v] (scalar per-lane m/l, 2-shfl reduce),
// 2-term scores (vh+vl)*qh, m-split x2 with bf16 partials + merge kernel,
// m-tile 32 double-buffered global_load_lds staging (1 barrier/tile),
// head-per-XCD grid, defer-max rescale.

typedef __attribute__((ext_vector_type(8))) short short8;   // 8 x bf16 (4 VGPRs)
typedef __attribute__((ext_vector_type(4))) float f32x4;

#define MFMA(a,b,c) __builtin_amdgcn_mfma_f32_16x16x32_bf16((a),(b),(c),0,0,0)
#define LOG2E 1.44269504088896340736f
#define DEFER_THR 8.0f

#define AS1 __attribute__((address_space(1)))
#define AS3 __attribute__((address_space(3)))
static __device__ __forceinline__ void gld16(const void* g, void* l) {
  __builtin_amdgcn_global_load_lds((const AS1 void*)g, (AS3 void*)l, 16, 0, 0);
}

static __device__ __forceinline__ unsigned short f2bf(float f) {
  union { float f; unsigned u; } v; v.f = f;
  unsigned r = v.u + 0x7fffu + ((v.u >> 16) & 1u);   // round-to-nearest-even
  return (unsigned short)(r >> 16);
}
static __device__ __forceinline__ float bf2f(unsigned short h) {
  union { unsigned u; float f; } v; v.u = ((unsigned)h) << 16; return v.f;
}
static __device__ __forceinline__ void split2(float f, unsigned short& hi, unsigned short& lo) {
  hi = f2bf(f);
  lo = f2bf(f - bf2f(hi));
}

// ---------------- prep 1: x f32 -> bf16 hi/lo ----------------
__global__ __launch_bounds__(256) void kxbf(const float* __restrict__ x,
                                            unsigned short* __restrict__ xh,
                                            unsigned short* __restrict__ xl) {
  int i = blockIdx.x * 256 + threadIdx.x;      // 131072 float4s, grid=512
  float4 v = reinterpret_cast<const float4*>(x)[i];
  ushort4 oh, ol;
  split2(v.x, oh.x, ol.x); split2(v.y, oh.y, ol.y);
  split2(v.z, oh.z, ol.z); split2(v.w, oh.w, ol.w);
  reinterpret_cast<ushort4*>(xh)[i] = oh;
  reinterpret_cast<ushort4*>(xl)[i] = ol;
}

// ---------------- prep 2: transpose weights to bf16 hi/lo ----------------
// blocks 0..23: WTh/WTl[slot][h][e][d] = W[slot][h][d][e]  (slot 0=Wq,1=Wk,2=Wv)
// blocks 24..31: WoT[e][bb*128+k] = Wo[bb*128+k][e]  (hi only)
__global__ __launch_bounds__(256) void kwt(const float* __restrict__ Wq,
                                           const float* __restrict__ Wk,
                                           const float* __restrict__ Wv,
                                           const float* __restrict__ Wo,
                                           unsigned short* __restrict__ WTh,
                                           unsigned short* __restrict__ WTl,
                                           unsigned short* __restrict__ WoT) {
  __shared__ float lds[64 * 130];
  int b = blockIdx.x, t = threadIdx.x;
  const float* src; int isWo;
  if (b < 24) {
    int slot = b >> 3, hh = b & 7;
    src = (slot == 0 ? Wq : (slot == 1 ? Wk : Wv)) + hh * 16384;
    isWo = 0;
  } else {
    src = Wo + (b - 24) * 16384;
    isWo = 1;
  }
  for (int half = 0; half < 2; ++half) {
#pragma unroll
    for (int i = 0; i < 8; ++i) {              // stage 64 rows x 128 cols f32
      int lin = i * 1024 + t * 4;
      int row = lin >> 7, col = lin & 127;
      float4 v = *reinterpret_cast<const float4*>(src + half * 8192 + lin);
      lds[row * 130 + col + 0] = v.x;
      lds[row * 130 + col + 1] = v.y;
      lds[row * 130 + col + 2] = v.z;
      lds[row * 130 + col + 3] = v.w;
    }
    __syncthreads();
    int e = t >> 1, k0 = (t & 1) * 32;
    float buf[32];
#pragma unroll
    for (int j = 0; j < 32; ++j) buf[j] = lds[(k0 + j) * 130 + e];
    int kg = half * 64 + k0;
    if (!isWo) {
      unsigned short* dh = WTh + b * 16384 + e * 128 + kg;
      unsigned short* dl = WTl + b * 16384 + e * 128 + kg;
#pragma unroll
      for (int c = 0; c < 4; ++c) {
        short8 oh, ol;
#pragma unroll
        for (int jj = 0; jj < 8; ++jj) {
          unsigned short h, l; split2(buf[c * 8 + jj], h, l);
          oh[jj] = (short)h; ol[jj] = (short)l;
        }
        *reinterpret_cast<short8*>(dh + c * 8) = oh;
        *reinterpret_cast<short8*>(dl + c * 8) = ol;
      }
    } else {
      unsigned short* dst = WoT + e * 1024 + (b - 24) * 128 + kg;
#pragma unroll
      for (int c = 0; c < 4; ++c) {
        short8 o;
#pragma unroll
        for (int jj = 0; jj < 8; ++jj) o[jj] = (short)f2bf(buf[c * 8 + jj]);
        *reinterpret_cast<short8*>(dst + c * 8) = o;
      }
    }
    __syncthreads();
  }
}

// ---------------- projections ----------------
// z=0 -> Qh[h][n][e] (3-term, hi-only store), z=1 -> Vh/Vl[h][n][e] (3-term),
// z=2 -> Kt[h][e][n] (plain, transposed via LDS)
__global__ __launch_bounds__(256) void kproj(const unsigned short* __restrict__ xh,
                                             const unsigned short* __restrict__ xl,
                                             const unsigned short* __restrict__ WThg,
                                             const unsigned short* __restrict__ WTlg,
                                             const float* __restrict__ bq,
                                             const float* __restrict__ bk,
                                             const float* __restrict__ bv,
                                             unsigned short* __restrict__ Qh,
                                             unsigned short* __restrict__ Vh,
                                             unsigned short* __restrict__ Vl,
                                             unsigned short* __restrict__ Kt) {
  __shared__ __align__(16) unsigned char lds[64 * 128 * 2];
  int nb = blockIdx.x, h = blockIdx.y, z = blockIdx.z;
  int t = threadIdx.x, lane = t & 63, w = t >> 6;
  int r = lane & 15, g = lane >> 4;
  int slot = (z == 0) ? 0 : (z == 1 ? 2 : 1);
  const unsigned short* Wth = WThg + (slot * 8 + h) * 16384;   // [e][d]
  const unsigned short* Wtl = WTlg + (slot * 8 + h) * 16384;
  const float* bias = (z == 0) ? bq : (z == 1 ? bv : bk);
  int rowbase = nb * 64 + w * 16;

  short8 ah[4], al[4];
#pragma unroll
  for (int kc = 0; kc < 4; ++kc) {
    ah[kc] = *reinterpret_cast<const short8*>(xh + (rowbase + r) * 128 + kc * 32 + g * 8);
    al[kc] = *reinterpret_cast<const short8*>(xl + (rowbase + r) * 128 + kc * 32 + g * 8);
  }
  f32x4 acc[8];
#pragma unroll
  for (int ct = 0; ct < 8; ++ct) acc[ct] = (f32x4){0.f, 0.f, 0.f, 0.f};
  if (z < 2) {
#pragma unroll
    for (int ct = 0; ct < 8; ++ct) {
#pragma unroll
      for (int kc = 0; kc < 4; ++kc) {
        short8 bh = *reinterpret_cast<const short8*>(Wth + (ct * 16 + r) * 128 + kc * 32 + g * 8);
        short8 bl = *reinterpret_cast<const short8*>(Wtl + (ct * 16 + r) * 128 + kc * 32 + g * 8);
        acc[ct] = MFMA(ah[kc], bh, acc[ct]);
        acc[ct] = MFMA(ah[kc], bl, acc[ct]);
        acc[ct] = MFMA(al[kc], bh, acc[ct]);
      }
    }
    unsigned short* dh = ((z == 0) ? Qh : Vh) + (size_t)h * 4096 * 128;
    unsigned short* dl = Vl + (size_t)h * 4096 * 128;
#pragma unroll
    for (int ct = 0; ct < 8; ++ct) {
      int e = ct * 16 + r;
      float bb = bias[h * 128 + e];
#pragma unroll
      for (int rr = 0; rr < 4; ++rr) {
        int n = rowbase + g * 4 + rr;
        float fv = acc[ct][rr] + bb;
        if (z == 0) {
          dh[n * 128 + e] = f2bf(fv);
        } else {
          unsigned short hi_, lo_; split2(fv, hi_, lo_);
          dh[n * 128 + e] = hi_;
          dl[n * 128 + e] = lo_;
        }
      }
    }
  } else {
#pragma unroll
    for (int ct = 0; ct < 8; ++ct) {
#pragma unroll
      for (int kc = 0; kc < 4; ++kc) {
        short8 bh = *reinterpret_cast<const short8*>(Wth + (ct * 16 + r) * 128 + kc * 32 + g * 8);
        acc[ct] = MFMA(ah[kc], bh, acc[ct]);
      }
    }
    // write C into swizzled LDS, then stream out transposed as Kt[h][e][n]
#pragma unroll
    for (int ct = 0; ct < 8; ++ct) {
      int e = ct * 16 + r;
      float bb = bias[h * 128 + e];
#pragma unroll
      for (int rr = 0; rr < 4; ++rr) {
        int n = w * 16 + g * 4 + rr;
        unsigned off = ((unsigned)(n * 128 + e) * 2u) ^ ((unsigned)(n & 7) << 4);
        *reinterpret_cast<unsigned short*>(lds + off) = f2bf(acc[ct][rr] + bb);
      }
    }
    __syncthreads();
    int e = t >> 1, n0 = (t & 1) * 32;
    unsigned short buf[32];
#pragma unroll
    for (int j = 0; j < 32; ++j) {
      int n = n0 + j;
      unsigned off = ((unsigned)(n * 128 + e) * 2u) ^ ((unsigned)(n & 7) << 4);
      buf[j] = *reinterpret_cast<unsigned short*>(lds + off);
    }
    unsigned short* dst = Kt + ((size_t)h * 128 + e) * 4096 + nb * 64 + n0;
#pragma unroll
    for (int c = 0; c < 4; ++c) {
      short8 o;
#pragma unroll
      for (int jj = 0; jj < 8; ++jj) o[jj] = (short)buf[c * 8 + jj];
      *reinterpret_cast<short8*>(dst + c * 8) = o;
    }
  }
}

// ---------------- flash attention, swapped operands, m-split x2 ----------------
// grid (8 heads, 64 n-blocks, 2 m-halves); 4 waves x 16 v-rows.
// scores C[m][v] = MFMA(Qfrag, Vfrag); PV out^T C[d][v] = MFMA(Kfrag, Pfrag).
// Writes unnormalized bf16 partials + (m,l) per (z,h,n).
__global__ __launch_bounds__(256, 4) void kattn(
    const unsigned short* __restrict__ Qg,   // [h][n][d] bf16
    const unsigned short* __restrict__ Kt,   // [h][d][n] bf16
    const unsigned short* __restrict__ Vh,   // [h][n][d] bf16 hi
    const unsigned short* __restrict__ Vl,   // [h][n][d] bf16 lo
    unsigned short* __restrict__ Opart,      // [z][h][n][d] bf16 (unnormalized)
    float2* __restrict__ ml) {               // [z][h][n] = {m, l}
  __shared__ __align__(16) unsigned char qlds[2][8192];   // [buf][32m][256B] swizzled
  __shared__ __align__(16) unsigned char klds[2][8192];   // [buf][128d][64B] linear
  __shared__ __align__(16) unsigned short plds[4][16 * 40]; // per-wave P[v=r][m], stride 40
  const int h = blockIdx.x, nb = blockIdx.y, z = blockIdx.z;
  const int t = threadIdx.x, lane = t & 63, w = t >> 6;
  const int r = lane & 15, g = lane >> 4;
  const unsigned char* Qb = (const unsigned char*)(Qg + (size_t)h * 4096 * 128);
  const unsigned char* Kb = (const unsigned char*)(Kt + (size_t)h * 128 * 4096);

  // staging maps (per thread)
  const int qrow = t >> 4;                       // 0..15 (+16 for j=1)
  const unsigned qcb = (unsigned)((t & 15) * 16);
  const int krow = t >> 2;                       // 0..63 (+64)
  const unsigned kmb = (unsigned)((t & 3) * 16);

  const int vrow = nb * 64 + w * 16 + r;
  short8 vah[4], val[4];
#pragma unroll
  for (int kc = 0; kc < 4; ++kc) {
    vah[kc] = *reinterpret_cast<const short8*>(Vh + (size_t)h * 4096 * 128 + (size_t)vrow * 128 + kc * 32 + g * 8);
    val[kc] = *reinterpret_cast<const short8*>(Vl + (size_t)h * 4096 * 128 + (size_t)vrow * 128 + kc * 32 + g * 8);
  }

  f32x4 oacc[8];
#pragma unroll
  for (int dt = 0; dt < 8; ++dt) oacc[dt] = (f32x4){0.f, 0.f, 0.f, 0.f};
  float mrun = -3e38f, lrun = 0.f;
  const int mt0 = z * 64;                        // 64 tiles of 32 m per half

#define STAGE(buf, mtile) do {                                                   \
    const size_t mQ = (size_t)(mtile) * 32 * 256;                                \
    const size_t mK = (size_t)(mtile) * 32 * 2;                                  \
    _Pragma("unroll")                                                            \
    for (int j = 0; j < 2; ++j) {                                                \
      int row = qrow + j * 16;                                                   \
      gld16(Qb + mQ + (size_t)row * 256 + (qcb ^ ((unsigned)(row & 7) << 4)),    \
            &qlds[buf][j * 4096 + t * 16]);                                      \
    }                                                                            \
    _Pragma("unroll")                                                            \
    for (int j = 0; j < 2; ++j) {                                                \
      int d = krow + j * 64;                                                     \
      gld16(Kb + (size_t)d * 8192 + mK + kmb,                                    \
            &klds[buf][j * 4096 + t * 16]);                                      \
    }                                                                            \
  } while (0)

  STAGE(0, mt0);
  __syncthreads();

  const unsigned qsw = ((unsigned)(r & 7)) << 4;
  for (int it = 0; it < 64; ++it) {
    const int buf = it & 1;
    if (it < 63) STAGE(buf ^ 1, mt0 + it + 1);
    // ---- scores: C[m (32)][v (16)] over k=d=128, 2-term (vh + vl) ----
    f32x4 s0 = (f32x4){0.f, 0.f, 0.f, 0.f};
    f32x4 s1 = (f32x4){0.f, 0.f, 0.f, 0.f};
    __builtin_amdgcn_s_setprio(1);
#pragma unroll
    for (int kc = 0; kc < 4; ++kc) {
      unsigned col = (unsigned)(kc * 64 + g * 16);
      short8 q0 = *reinterpret_cast<const short8*>(&qlds[buf][(unsigned)r * 256 + (col ^ qsw)]);
      short8 q1 = *reinterpret_cast<const short8*>(&qlds[buf][(unsigned)(16 + r) * 256 + (col ^ qsw)]);
      s0 = MFMA(q0, vah[kc], s0);
      s1 = MFMA(q1, vah[kc], s1);
      s0 = MFMA(q0, val[kc], s0);
      s1 = MFMA(q1, val[kc], s1);
    }
    __builtin_amdgcn_s_setprio(0);
    // ---- online softmax; per-lane scalar m/l for v=r ----
    float mx = fmaxf(fmaxf(fmaxf(s0[0], s0[1]), fmaxf(s0[2], s0[3])),
                     fmaxf(fmaxf(s1[0], s1[1]), fmaxf(s1[2], s1[3])));
    mx = fmaxf(mx, __shfl_xor(mx, 16));
    mx = fmaxf(mx, __shfl_xor(mx, 32));
    if (__any(mx > mrun + DEFER_THR)) {
      float nm = fmaxf(mrun, mx);
      float sc = exp2f((mrun - nm) * LOG2E);
      lrun *= sc;
#pragma unroll
      for (int dt = 0; dt < 8; ++dt) oacc[dt] *= sc;
      mrun = nm;
    }
    float p[8];
#pragma unroll
    for (int j = 0; j < 4; ++j) {
      p[j]     = exp2f((s0[j] - mrun) * LOG2E);
      p[4 + j] = exp2f((s1[j] - mrun) * LOG2E);
    }
    float ps = ((p[0] + p[1]) + (p[2] + p[3])) + ((p[4] + p[5]) + (p[6] + p[7]));
    ps += __shfl_xor(ps, 16);
    ps += __shfl_xor(ps, 32);
    lrun += ps;
    // ---- P -> plds[v=r][m], two 8B packed writes ----
    ushort4 pk0, pk1;
    pk0.x = f2bf(p[0]); pk0.y = f2bf(p[1]); pk0.z = f2bf(p[2]); pk0.w = f2bf(p[3]);
    pk1.x = f2bf(p[4]); pk1.y = f2bf(p[5]); pk1.z = f2bf(p[6]); pk1.w = f2bf(p[7]);
    unsigned short* pw = &plds[w][r * 40];
    *reinterpret_cast<ushort4*>(pw + g * 4)      = pk0;
    *reinterpret_cast<ushort4*>(pw + 16 + g * 4) = pk1;
    short8 pa = *reinterpret_cast<const short8*>(&plds[w][r * 40 + g * 8]);
    // ---- PV: out^T C[d][v] += K[d][m] * P[v][m] ----
    __builtin_amdgcn_s_setprio(1);
#pragma unroll
    for (int dt = 0; dt < 8; ++dt) {
      short8 kb = *reinterpret_cast<const short8*>(&klds[buf][(unsigned)(dt * 16 + r) * 64 + (unsigned)(g * 16)]);
      oacc[dt] = MFMA(kb, pa, oacc[dt]);
    }
    __builtin_amdgcn_s_setprio(0);
    __syncthreads();
  }
#undef STAGE
  // epilogue: unnormalized bf16 partial + (m,l)
  unsigned short* Ob = Opart + ((size_t)(z * 8 + h) * 4096 + vrow) * 128;
#pragma unroll
  for (int dt = 0; dt < 8; ++dt) {
    ushort4 o4;
    o4.x = f2bf(oacc[dt][0]); o4.y = f2bf(oacc[dt][1]);
    o4.z = f2bf(oacc[dt][2]); o4.w = f2bf(oacc[dt][3]);
    *reinterpret_cast<ushort4*>(Ob + dt * 16 + g * 4) = o4;
  }
  if (g == 0) ml[(size_t)(z * 8 + h) * 4096 + vrow] = make_float2(mrun, lrun);
}

// ---------------- merge the two m-halves -> OUTS[n][h*128+d] bf16 ----------------
__global__ __launch_bounds__(256) void kmerge(const unsigned short* __restrict__ Opart,
                                              const float2* __restrict__ ml,
                                              unsigned short* __restrict__ OUTS) {
  int tid = blockIdx.x * 256 + threadIdx.x;      // 1048576 threads, grid=4096
  int q = tid & 31, n = (tid >> 5) & 4095, h = tid >> 17;
  float2 ml0 = ml[(size_t)h * 4096 + n];
  float2 ml1 = ml[(size_t)(8 + h) * 4096 + n];
  float M = fmaxf(ml0.x, ml1.x);
  float a0 = exp2f((ml0.x - M) * LOG2E);
  float a1 = exp2f((ml1.x - M) * LOG2E);
  float inv = 1.0f / (ml0.y * a0 + ml1.y * a1);
  a0 *= inv; a1 *= inv;
  ushort4 o0 = *reinterpret_cast<const ushort4*>(Opart + ((size_t)h * 4096 + n) * 128 + q * 4);
  ushort4 o1 = *reinterpret_cast<const ushort4*>(Opart + ((size_t)(8 + h) * 4096 + n) * 128 + q * 4);
  ushort4 o;
  o.x = f2bf(bf2f(o0.x) * a0 + bf2f(o1.x) * a1);
  o.y = f2bf(bf2f(o0.y) * a0 + bf2f(o1.y) * a1);
  o.z = f2bf(bf2f(o0.z) * a0 + bf2f(o1.z) * a1);
  o.w = f2bf(bf2f(o0.w) * a0 + bf2f(o1.w) * a1);
  *reinterpret_cast<ushort4*>(OUTS + (size_t)n * 1024 + h * 128 + q * 4) = o;
}

// ---------------- output projection ----------------
__global__ __launch_bounds__(256) void kout(const unsigned short* __restrict__ OUTS,
                                            const unsigned short* __restrict__ WoT,
                                            const float* __restrict__ bo,
                                            float* __restrict__ out) {
  int rb = blockIdx.x, ch = blockIdx.y;
  int t = threadIdx.x, lane = t & 63, w = t >> 6;
  int r = lane & 15, g = lane >> 4;
  int row = rb * 16 + r;
  int e0 = ch * 64 + w * 16;
  f32x4 acc = (f32x4){0.f, 0.f, 0.f, 0.f};
#pragma unroll
  for (int kc = 0; kc < 32; ++kc) {
    short8 a = *reinterpret_cast<const short8*>(OUTS + (size_t)row * 1024 + kc * 32 + g * 8);
    short8 b = *reinterpret_cast<const short8*>(WoT + (size_t)(e0 + r) * 1024 + kc * 32 + g * 8);
    acc = MFMA(a, b, acc);
  }
  float bov = bo[e0 + r];
#pragma unroll
  for (int rr = 0; rr < 4; ++rr) {
    int n = rb * 16 + g * 4 + rr;
    out[(size_t)n * 128 + e0 + r] = acc[rr] + bov;
  }
}

extern "C" void kernel_launch(void* const* d_in, const int* in_sizes, int n_in,
                              void* d_out, int out_size, void* d_ws, size_t ws_size,
                              hipStream_t stream) {
  const float* x  = (const float*)d_in[0];
  const float* Wq = (const float*)d_in[1];
  const float* bq = (const float*)d_in[2];
  const float* Wk = (const float*)d_in[3];
  const float* bk = (const float*)d_in[4];
  const float* Wv = (const float*)d_in[5];
  const float* bv = (const float*)d_in[6];
  const float* Wo = (const float*)d_in[7];
  const float* bo = (const float*)d_in[8];
  float* out = (float*)d_out;

  unsigned short* ws = (unsigned short*)d_ws;    // ~63.2 MB
  unsigned short* xh    = ws;                    // 524288
  unsigned short* xl    = xh + 524288;           // 524288
  unsigned short* WTh   = xl + 524288;           // 393216
  unsigned short* WTl   = WTh + 393216;          // 393216
  unsigned short* WoT   = WTl + 393216;          // 131072
  unsigned short* Qh    = WoT + 131072;          // 4194304
  unsigned short* Vh    = Qh + 4194304;          // 4194304
  unsigned short* Vl    = Vh + 4194304;          // 4194304
  unsigned short* Kt    = Vl + 4194304;          // 4194304
  unsigned short* OUTS  = Kt + 4194304;          // 4194304
  unsigned short* Opart = OUTS + 4194304;        // 8388608
  float2*         mlp   = (float2*)(Opart + 8388608);  // 65536 float2

  kxbf<<<512, 256, 0, stream>>>(x, xh, xl);
  kwt<<<32, 256, 0, stream>>>(Wq, Wk, Wv, Wo, WTh, WTl, WoT);
  kproj<<<dim3(64, 8, 3), 256, 0, stream>>>(xh, xl, WTh, WTl, bq, bk, bv,
                                            Qh, Vh, Vl, Kt);
  kattn<<<dim3(8, 64, 2), 256, 0, stream>>>(Qh, Kt, Vh, Vl, Opart, mlp);
  kmerge<<<4096, 256, 0, stream>>>(Opart, mlp, OUTS);
  kout<<<dim3(256, 2), 256, 0, stream>>>(OUTS, WoT, bo, out);
}

// Round 4
// 275.371 us; speedup vs baseline: 1.5529x; 1.0364x over previous
//
#include <hip/hip_runtime.h>
#include <hip/hip_bf16.h>

// SelfAttention_592705487560 — N=4096, D=128, H=8
// scores = V·Q^T (flash roles: query=v, key=q, value=k), softmax over q-index.
// Round 4: kattn with 32 v-rows/wave (2-wave blocks, 4 blocks/CU) — halves
// LDS+staging per MFMA; kxbf fused into kprojf; kmerge fused into koutm.
// ws (ushort units): WTh 393216 | WTl 393216 | WoT 131072 | Qh/Vh/Vl/Kt 4M ea |
//                    Opart 8M | ml 65536 float2  => ~52.7 MB

typedef __attribute__((ext_vector_type(8))) short short8;   // 8 x bf16 (4 VGPRs)
typedef __attribute__((ext_vector_type(4))) float f32x4;

#define MFMA(a,b,c) __builtin_amdgcn_mfma_f32_16x16x32_bf16((a),(b),(c),0,0,0)
#define LOG2E 1.44269504088896340736f
#define DEFER_THR 8.0f

#define AS1 __attribute__((address_space(1)))
#define AS3 __attribute__((address_space(3)))
static __device__ __forceinline__ void gld16(const void* g, void* l) {
  __builtin_amdgcn_global_load_lds((const AS1 void*)g, (AS3 void*)l, 16, 0, 0);
}

static __device__ __forceinline__ unsigned short f2bf(float f) {
  union { float f; unsigned u; } v; v.f = f;
  unsigned r = v.u + 0x7fffu + ((v.u >> 16) & 1u);   // round-to-nearest-even
  return (unsigned short)(r >> 16);
}
static __device__ __forceinline__ float bf2f(unsigned short h) {
  union { unsigned u; float f; } v; v.u = ((unsigned)h) << 16; return v.f;
}
static __device__ __forceinline__ void split2(float f, unsigned short& hi, unsigned short& lo) {
  hi = f2bf(f);
  lo = f2bf(f - bf2f(hi));
}

// ---------------- prep: transpose weights to bf16 hi/lo ----------------
// blocks 0..23: WTh/WTl[slot][h][e][d] = W[slot][h][d][e]  (slot 0=Wq,1=Wk,2=Wv)
// blocks 24..31: WoT[e][bb*128+k] = Wo[bb*128+k][e]  (hi only)
__global__ __launch_bounds__(256) void kwt(const float* __restrict__ Wq,
                                           const float* __restrict__ Wk,
                                           const float* __restrict__ Wv,
                                           const float* __restrict__ Wo,
                                           unsigned short* __restrict__ WTh,
                                           unsigned short* __restrict__ WTl,
                                           unsigned short* __restrict__ WoT) {
  __shared__ float lds[64 * 130];
  int b = blockIdx.x, t = threadIdx.x;
  const float* src; int isWo;
  if (b < 24) {
    int slot = b >> 3, hh = b & 7;
    src = (slot == 0 ? Wq : (slot == 1 ? Wk : Wv)) + hh * 16384;
    isWo = 0;
  } else {
    src = Wo + (b - 24) * 16384;
    isWo = 1;
  }
  for (int half = 0; half < 2; ++half) {
#pragma unroll
    for (int i = 0; i < 8; ++i) {              // stage 64 rows x 128 cols f32
      int lin = i * 1024 + t * 4;
      int row = lin >> 7, col = lin & 127;
      float4 v = *reinterpret_cast<const float4*>(src + half * 8192 + lin);
      lds[row * 130 + col + 0] = v.x;
      lds[row * 130 + col + 1] = v.y;
      lds[row * 130 + col + 2] = v.z;
      lds[row * 130 + col + 3] = v.w;
    }
    __syncthreads();
    int e = t >> 1, k0 = (t & 1) * 32;
    float buf[32];
#pragma unroll
    for (int j = 0; j < 32; ++j) buf[j] = lds[(k0 + j) * 130 + e];
    int kg = half * 64 + k0;
    if (!isWo) {
      unsigned short* dh = WTh + b * 16384 + e * 128 + kg;
      unsigned short* dl = WTl + b * 16384 + e * 128 + kg;
#pragma unroll
      for (int c = 0; c < 4; ++c) {
        short8 oh, ol;
#pragma unroll
        for (int jj = 0; jj < 8; ++jj) {
          unsigned short h, l; split2(buf[c * 8 + jj], h, l);
          oh[jj] = (short)h; ol[jj] = (short)l;
        }
        *reinterpret_cast<short8*>(dh + c * 8) = oh;
        *reinterpret_cast<short8*>(dl + c * 8) = ol;
      }
    } else {
      unsigned short* dst = WoT + e * 1024 + (b - 24) * 128 + kg;
#pragma unroll
      for (int c = 0; c < 4; ++c) {
        short8 o;
#pragma unroll
        for (int jj = 0; jj < 8; ++jj) o[jj] = (short)f2bf(buf[c * 8 + jj]);
        *reinterpret_cast<short8*>(dst + c * 8) = o;
      }
    }
    __syncthreads();
  }
}

// ---------------- fused projections (reads f32 x, splits inline) ----------------
// grid (64 nb, 8 h). Q (3-term, hi store), V (3-term, hi/lo), K (1-term, ->Kt).
__global__ __launch_bounds__(256) void kprojf(const float* __restrict__ x,
                                              const unsigned short* __restrict__ WThg,
                                              const unsigned short* __restrict__ WTlg,
                                              const float* __restrict__ bq,
                                              const float* __restrict__ bk,
                                              const float* __restrict__ bv,
                                              unsigned short* __restrict__ Qh,
                                              unsigned short* __restrict__ Vh,
                                              unsigned short* __restrict__ Vl,
                                              unsigned short* __restrict__ Kt) {
  __shared__ __align__(16) unsigned char lds[64 * 128 * 2];
  int nb = blockIdx.x, h = blockIdx.y;
  int t = threadIdx.x, lane = t & 63, w = t >> 6;
  int r = lane & 15, g = lane >> 4;
  int rowbase = nb * 64 + w * 16;

  // x rows -> hi/lo fragments in registers
  short8 ah[4], al[4];
#pragma unroll
  for (int kc = 0; kc < 4; ++kc) {
    const float* xp = x + (size_t)(rowbase + r) * 128 + kc * 32 + g * 8;
    float4 f0 = *reinterpret_cast<const float4*>(xp);
    float4 f1 = *reinterpret_cast<const float4*>(xp + 4);
    unsigned short hi_, lo_;
    split2(f0.x, hi_, lo_); ah[kc][0] = (short)hi_; al[kc][0] = (short)lo_;
    split2(f0.y, hi_, lo_); ah[kc][1] = (short)hi_; al[kc][1] = (short)lo_;
    split2(f0.z, hi_, lo_); ah[kc][2] = (short)hi_; al[kc][2] = (short)lo_;
    split2(f0.w, hi_, lo_); ah[kc][3] = (short)hi_; al[kc][3] = (short)lo_;
    split2(f1.x, hi_, lo_); ah[kc][4] = (short)hi_; al[kc][4] = (short)lo_;
    split2(f1.y, hi_, lo_); ah[kc][5] = (short)hi_; al[kc][5] = (short)lo_;
    split2(f1.z, hi_, lo_); ah[kc][6] = (short)hi_; al[kc][6] = (short)lo_;
    split2(f1.w, hi_, lo_); ah[kc][7] = (short)hi_; al[kc][7] = (short)lo_;
  }

  f32x4 acc[8];
  // ---- Q (slot 0): 3-term, store hi only ----
  {
    const unsigned short* Wth = WThg + (0 * 8 + h) * 16384;
    const unsigned short* Wtl = WTlg + (0 * 8 + h) * 16384;
#pragma unroll
    for (int ct = 0; ct < 8; ++ct) acc[ct] = (f32x4){0.f, 0.f, 0.f, 0.f};
#pragma unroll
    for (int ct = 0; ct < 8; ++ct) {
#pragma unroll
      for (int kc = 0; kc < 4; ++kc) {
        short8 bh = *reinterpret_cast<const short8*>(Wth + (ct * 16 + r) * 128 + kc * 32 + g * 8);
        short8 bl = *reinterpret_cast<const short8*>(Wtl + (ct * 16 + r) * 128 + kc * 32 + g * 8);
        acc[ct] = MFMA(ah[kc], bh, acc[ct]);
        acc[ct] = MFMA(ah[kc], bl, acc[ct]);
        acc[ct] = MFMA(al[kc], bh, acc[ct]);
      }
    }
    unsigned short* dh = Qh + (size_t)h * 4096 * 128;
#pragma unroll
    for (int ct = 0; ct < 8; ++ct) {
      int e = ct * 16 + r;
      float bb = bq[h * 128 + e];
#pragma unroll
      for (int rr = 0; rr < 4; ++rr) {
        int n = rowbase + g * 4 + rr;
        dh[n * 128 + e] = f2bf(acc[ct][rr] + bb);
      }
    }
  }
  // ---- V (slot 2): 3-term, store hi/lo ----
  {
    const unsigned short* Wth = WThg + (2 * 8 + h) * 16384;
    const unsigned short* Wtl = WTlg + (2 * 8 + h) * 16384;
#pragma unroll
    for (int ct = 0; ct < 8; ++ct) acc[ct] = (f32x4){0.f, 0.f, 0.f, 0.f};
#pragma unroll
    for (int ct = 0; ct < 8; ++ct) {
#pragma unroll
      for (int kc = 0; kc < 4; ++kc) {
        short8 bh = *reinterpret_cast<const short8*>(Wth + (ct * 16 + r) * 128 + kc * 32 + g * 8);
        short8 bl = *reinterpret_cast<const short8*>(Wtl + (ct * 16 + r) * 128 + kc * 32 + g * 8);
        acc[ct] = MFMA(ah[kc], bh, acc[ct]);
        acc[ct] = MFMA(ah[kc], bl, acc[ct]);
        acc[ct] = MFMA(al[kc], bh, acc[ct]);
      }
    }
    unsigned short* dh = Vh + (size_t)h * 4096 * 128;
    unsigned short* dl = Vl + (size_t)h * 4096 * 128;
#pragma unroll
    for (int ct = 0; ct < 8; ++ct) {
      int e = ct * 16 + r;
      float bb = bv[h * 128 + e];
#pragma unroll
      for (int rr = 0; rr < 4; ++rr) {
        int n = rowbase + g * 4 + rr;
        unsigned short hi_, lo_; split2(acc[ct][rr] + bb, hi_, lo_);
        dh[n * 128 + e] = hi_;
        dl[n * 128 + e] = lo_;
      }
    }
  }
  // ---- K (slot 1): 1-term, transpose via LDS -> Kt[h][e][n] ----
  {
    const unsigned short* Wth = WThg + (1 * 8 + h) * 16384;
#pragma unroll
    for (int ct = 0; ct < 8; ++ct) acc[ct] = (f32x4){0.f, 0.f, 0.f, 0.f};
#pragma unroll
    for (int ct = 0; ct < 8; ++ct) {
#pragma unroll
      for (int kc = 0; kc < 4; ++kc) {
        short8 bh = *reinterpret_cast<const short8*>(Wth + (ct * 16 + r) * 128 + kc * 32 + g * 8);
        acc[ct] = MFMA(ah[kc], bh, acc[ct]);
      }
    }
#pragma unroll
    for (int ct = 0; ct < 8; ++ct) {
      int e = ct * 16 + r;
      float bb = bk[h * 128 + e];
#pragma unroll
      for (int rr = 0; rr < 4; ++rr) {
        int n = w * 16 + g * 4 + rr;
        unsigned off = ((unsigned)(n * 128 + e) * 2u) ^ ((unsigned)(n & 7) << 4);
        *reinterpret_cast<unsigned short*>(lds + off) = f2bf(acc[ct][rr] + bb);
      }
    }
    __syncthreads();
    int e = t >> 1, n0 = (t & 1) * 32;
    unsigned short buf[32];
#pragma unroll
    for (int j = 0; j < 32; ++j) {
      int n = n0 + j;
      unsigned off = ((unsigned)(n * 128 + e) * 2u) ^ ((unsigned)(n & 7) << 4);
      buf[j] = *reinterpret_cast<unsigned short*>(lds + off);
    }
    unsigned short* dst = Kt + ((size_t)h * 128 + e) * 4096 + nb * 64 + n0;
#pragma unroll
    for (int c = 0; c < 4; ++c) {
      short8 o;
#pragma unroll
      for (int jj = 0; jj < 8; ++jj) o[jj] = (short)buf[c * 8 + jj];
      *reinterpret_cast<short8*>(dst + c * 8) = o;
    }
  }
}

// ---------------- flash attention: 2 waves x 32 v-rows, m-split x2 ----------------
// grid (8 h, 64 nb, 2 z); 128 threads. Unnormalized bf16 partials + (m,l).
__global__ __launch_bounds__(128, 2) void kattn(
    const unsigned short* __restrict__ Qg,   // [h][n][d] bf16
    const unsigned short* __restrict__ Kt,   // [h][d][n] bf16
    const unsigned short* __restrict__ Vh,   // [h][n][d] bf16 hi
    const unsigned short* __restrict__ Vl,   // [h][n][d] bf16 lo
    unsigned short* __restrict__ Opart,      // [z][h][n][d] bf16 (unnormalized)
    float2* __restrict__ ml) {               // [z][h][n] = {m, l}
  __shared__ __align__(16) unsigned char qlds[2][8192];     // [buf][32m][256B] swizzled
  __shared__ __align__(16) unsigned char klds[2][8192];     // [buf][128d][64B] linear
  __shared__ __align__(16) unsigned short plds[2][32 * 40]; // per-wave P[v][m], stride 40
  const int h = blockIdx.x, nb = blockIdx.y, z = blockIdx.z;
  const int t = threadIdx.x, lane = t & 63, w = t >> 6;
  const int r = lane & 15, g = lane >> 4;
  const unsigned char* Qb = (const unsigned char*)(Qg + (size_t)h * 4096 * 128);
  const unsigned char* Kb = (const unsigned char*)(Kt + (size_t)h * 128 * 4096);

  // V fragments for 32 rows (two v-blocks)
  const int vbase = nb * 64 + w * 32;
  short8 va0h[4], va0l[4], va1h[4], va1l[4];
#pragma unroll
  for (int kc = 0; kc < 4; ++kc) {
    size_t o0 = (size_t)h * 4096 * 128 + (size_t)(vbase + r) * 128 + kc * 32 + g * 8;
    size_t o1 = (size_t)h * 4096 * 128 + (size_t)(vbase + 16 + r) * 128 + kc * 32 + g * 8;
    va0h[kc] = *reinterpret_cast<const short8*>(Vh + o0);
    va0l[kc] = *reinterpret_cast<const short8*>(Vl + o0);
    va1h[kc] = *reinterpret_cast<const short8*>(Vh + o1);
    va1l[kc] = *reinterpret_cast<const short8*>(Vl + o1);
  }

  f32x4 oacc0[8], oacc1[8];
#pragma unroll
  for (int dt = 0; dt < 8; ++dt) {
    oacc0[dt] = (f32x4){0.f, 0.f, 0.f, 0.f};
    oacc1[dt] = (f32x4){0.f, 0.f, 0.f, 0.f};
  }
  float m0run = -3e38f, l0run = 0.f, m1run = -3e38f, l1run = 0.f;
  const int mt0 = z * 64;

#define STAGE(buf, mtile) do {                                                   \
    const unsigned char* qsrc = Qb + (size_t)(mtile) * 8192;                     \
    const unsigned char* ksrc = Kb + (size_t)(mtile) * 64;                       \
    _Pragma("unroll")                                                            \
    for (int j = 0; j < 4; ++j) {                                                \
      int row = j * 8 + (t >> 4);                                                \
      gld16(qsrc + (size_t)row * 256 + (((unsigned)(t & 15) * 16) ^ ((unsigned)(row & 7) << 4)), \
            &qlds[buf][j * 2048 + t * 16]);                                      \
    }                                                                            \
    _Pragma("unroll")                                                            \
    for (int j = 0; j < 4; ++j) {                                                \
      int row = j * 32 + (t >> 2);                                               \
      gld16(ksrc + (size_t)row * 8192 + (unsigned)(t & 3) * 16,                  \
            &klds[buf][j * 2048 + t * 16]);                                      \
    }                                                                            \
  } while (0)

  STAGE(0, mt0);
  __syncthreads();

  const unsigned qsw = ((unsigned)(r & 7)) << 4;
  for (int it = 0; it < 64; ++it) {
    const int buf = it & 1;
    if (it < 63) STAGE(buf ^ 1, mt0 + it + 1);
    // ---- scores: 4 C-tiles [m 32][v 32], 2-term (vh + vl) ----
    f32x4 s00 = (f32x4){0.f, 0.f, 0.f, 0.f};
    f32x4 s10 = (f32x4){0.f, 0.f, 0.f, 0.f};
    f32x4 s01 = (f32x4){0.f, 0.f, 0.f, 0.f};
    f32x4 s11 = (f32x4){0.f, 0.f, 0.f, 0.f};
    __builtin_amdgcn_s_setprio(1);
#pragma unroll
    for (int kc = 0; kc < 4; ++kc) {
      unsigned col = (unsigned)(kc * 64 + g * 16);
      short8 q0 = *reinterpret_cast<const short8*>(&qlds[buf][(unsigned)r * 256 + (col ^ qsw)]);
      short8 q1 = *reinterpret_cast<const short8*>(&qlds[buf][(unsigned)(16 + r) * 256 + (col ^ qsw)]);
      s00 = MFMA(q0, va0h[kc], s00);
      s10 = MFMA(q1, va0h[kc], s10);
      s01 = MFMA(q0, va1h[kc], s01);
      s11 = MFMA(q1, va1h[kc], s11);
      s00 = MFMA(q0, va0l[kc], s00);
      s10 = MFMA(q1, va0l[kc], s10);
      s01 = MFMA(q0, va1l[kc], s01);
      s11 = MFMA(q1, va1l[kc], s11);
    }
    __builtin_amdgcn_s_setprio(0);
    // ---- online softmax (per-lane scalar m/l; reduce over g via 2 shfl) ----
    float mx0 = fmaxf(fmaxf(fmaxf(s00[0], s00[1]), fmaxf(s00[2], s00[3])),
                      fmaxf(fmaxf(s10[0], s10[1]), fmaxf(s10[2], s10[3])));
    float mx1 = fmaxf(fmaxf(fmaxf(s01[0], s01[1]), fmaxf(s01[2], s01[3])),
                      fmaxf(fmaxf(s11[0], s11[1]), fmaxf(s11[2], s11[3])));
    mx0 = fmaxf(mx0, __shfl_xor(mx0, 16)); mx0 = fmaxf(mx0, __shfl_xor(mx0, 32));
    mx1 = fmaxf(mx1, __shfl_xor(mx1, 16)); mx1 = fmaxf(mx1, __shfl_xor(mx1, 32));
    if (__any(mx0 > m0run + DEFER_THR)) {
      float nm = fmaxf(m0run, mx0);
      float sc = exp2f((m0run - nm) * LOG2E);
      l0run *= sc;
#pragma unroll
      for (int dt = 0; dt < 8; ++dt) oacc0[dt] *= sc;
      m0run = nm;
    }
    if (__any(mx1 > m1run + DEFER_THR)) {
      float nm = fmaxf(m1run, mx1);
      float sc = exp2f((m1run - nm) * LOG2E);
      l1run *= sc;
#pragma unroll
      for (int dt = 0; dt < 8; ++dt) oacc1[dt] *= sc;
      m1run = nm;
    }
    float p0[8], p1[8];
#pragma unroll
    for (int j = 0; j < 4; ++j) {
      p0[j]     = exp2f((s00[j] - m0run) * LOG2E);
      p0[4 + j] = exp2f((s10[j] - m0run) * LOG2E);
      p1[j]     = exp2f((s01[j] - m1run) * LOG2E);
      p1[4 + j] = exp2f((s11[j] - m1run) * LOG2E);
    }
    float ps0 = ((p0[0] + p0[1]) + (p0[2] + p0[3])) + ((p0[4] + p0[5]) + (p0[6] + p0[7]));
    float ps1 = ((p1[0] + p1[1]) + (p1[2] + p1[3])) + ((p1[4] + p1[5]) + (p1[6] + p1[7]));
    ps0 += __shfl_xor(ps0, 16); ps0 += __shfl_xor(ps0, 32);
    ps1 += __shfl_xor(ps1, 16); ps1 += __shfl_xor(ps1, 32);
    l0run += ps0;
    l1run += ps1;
    // ---- P -> plds[v][m] (rows r / 16+r), packed 8B writes ----
    {
      ushort4 a, b, c, d;
      a.x = f2bf(p0[0]); a.y = f2bf(p0[1]); a.z = f2bf(p0[2]); a.w = f2bf(p0[3]);
      b.x = f2bf(p0[4]); b.y = f2bf(p0[5]); b.z = f2bf(p0[6]); b.w = f2bf(p0[7]);
      c.x = f2bf(p1[0]); c.y = f2bf(p1[1]); c.z = f2bf(p1[2]); c.w = f2bf(p1[3]);
      d.x = f2bf(p1[4]); d.y = f2bf(p1[5]); d.z = f2bf(p1[6]); d.w = f2bf(p1[7]);
      unsigned short* pw = &plds[w][0];
      *reinterpret_cast<ushort4*>(pw + r * 40 + g * 4)             = a;
      *reinterpret_cast<ushort4*>(pw + r * 40 + 16 + g * 4)        = b;
      *reinterpret_cast<ushort4*>(pw + (16 + r) * 40 + g * 4)      = c;
      *reinterpret_cast<ushort4*>(pw + (16 + r) * 40 + 16 + g * 4) = d;
    }
    short8 pa0 = *reinterpret_cast<const short8*>(&plds[w][r * 40 + g * 8]);
    short8 pa1 = *reinterpret_cast<const short8*>(&plds[w][(16 + r) * 40 + g * 8]);
    // ---- PV: out^T C[d][v] += K[d][m] * P[v][m]; kb shared across v-blocks ----
    __builtin_amdgcn_s_setprio(1);
#pragma unroll
    for (int dt = 0; dt < 8; ++dt) {
      short8 kb = *reinterpret_cast<const short8*>(&klds[buf][(unsigned)(dt * 16 + r) * 64 + (unsigned)(g * 16)]);
      oacc0[dt] = MFMA(kb, pa0, oacc0[dt]);
      oacc1[dt] = MFMA(kb, pa1, oacc1[dt]);
    }
    __builtin_amdgcn_s_setprio(0);
    __syncthreads();
  }
#undef STAGE
  // epilogue: unnormalized bf16 partials + (m,l)
  unsigned short* Ob = Opart + (size_t)(z * 8 + h) * 4096 * 128;
#pragma unroll
  for (int dt = 0; dt < 8; ++dt) {
#pragma unroll
    for (int rr = 0; rr < 4; ++rr) {
      int d = dt * 16 + g * 4 + rr;
      Ob[(size_t)(vbase + r) * 128 + d]      = f2bf(oacc0[dt][rr]);
      Ob[(size_t)(vbase + 16 + r) * 128 + d] = f2bf(oacc1[dt][rr]);
    }
  }
  if (g == 0) ml[(size_t)(z * 8 + h) * 4096 + vbase + r]      = make_float2(m0run, l0run);
  if (g == 1) ml[(size_t)(z * 8 + h) * 4096 + vbase + 16 + r] = make_float2(m1run, l1run);
}

// ---------------- fused merge + output projection ----------------
// grid (256); wave w -> e cols w*32..w*32+31; merges z-halves while building A.
__global__ __launch_bounds__(256) void koutm(const unsigned short* __restrict__ Opart,
                                             const float2* __restrict__ ml,
                                             const unsigned short* __restrict__ WoT,
                                             const float* __restrict__ bo,
                                             float* __restrict__ out) {
  int rb = blockIdx.x;
  int t = threadIdx.x, lane = t & 63, w = t >> 6;
  int r = lane & 15, g = lane >> 4;
  int row = rb * 16 + r;                         // A row (n index)
  float a0[8], a1[8];
#pragma unroll
  for (int h = 0; h < 8; ++h) {
    float2 m0 = ml[(size_t)h * 4096 + row];
    float2 m1 = ml[(size_t)(8 + h) * 4096 + row];
    float M = fmaxf(m0.x, m1.x);
    float e0 = exp2f((m0.x - M) * LOG2E);
    float e1 = exp2f((m1.x - M) * LOG2E);
    float inv = 1.0f / (m0.y * e0 + m1.y * e1);
    a0[h] = e0 * inv; a1[h] = e1 * inv;
  }
  f32x4 acc0 = (f32x4){0.f, 0.f, 0.f, 0.f};
  f32x4 acc1 = (f32x4){0.f, 0.f, 0.f, 0.f};
#pragma unroll
  for (int kc = 0; kc < 32; ++kc) {
    int h = kc >> 2;
    int dof = (kc & 3) * 32 + g * 8;
    short8 o0 = *reinterpret_cast<const short8*>(Opart + ((size_t)h * 4096 + row) * 128 + dof);
    short8 o1 = *reinterpret_cast<const short8*>(Opart + ((size_t)(8 + h) * 4096 + row) * 128 + dof);
    short8 af;
#pragma unroll
    for (int j = 0; j < 8; ++j)
      af[j] = (short)f2bf(bf2f((unsigned short)o0[j]) * a0[h] +
                          bf2f((unsigned short)o1[j]) * a1[h]);
    short8 b0 = *reinterpret_cast<const short8*>(WoT + (size_t)(w * 32 + r) * 1024 + kc * 32 + g * 8);
    short8 b1 = *reinterpret_cast<const short8*>(WoT + (size_t)(w * 32 + 16 + r) * 1024 + kc * 32 + g * 8);
    acc0 = MFMA(af, b0, acc0);
    acc1 = MFMA(af, b1, acc1);
  }
#pragma unroll
  for (int rr = 0; rr < 4; ++rr) {
    int n = rb * 16 + g * 4 + rr;
    out[(size_t)n * 128 + w * 32 + r]      = acc0[rr] + bo[w * 32 + r];
    out[(size_t)n * 128 + w * 32 + 16 + r] = acc1[rr] + bo[w * 32 + 16 + r];
  }
}

extern "C" void kernel_launch(void* const* d_in, const int* in_sizes, int n_in,
                              void* d_out, int out_size, void* d_ws, size_t ws_size,
                              hipStream_t stream) {
  const float* x  = (const float*)d_in[0];
  const float* Wq = (const float*)d_in[1];
  const float* bq = (const float*)d_in[2];
  const float* Wk = (const float*)d_in[3];
  const float* bk = (const float*)d_in[4];
  const float* Wv = (const float*)d_in[5];
  const float* bv = (const float*)d_in[6];
  const float* Wo = (const float*)d_in[7];
  const float* bo = (const float*)d_in[8];
  float* out = (float*)d_out;

  unsigned short* ws = (unsigned short*)d_ws;    // ~52.7 MB
  unsigned short* WTh   = ws;                    // 393216
  unsigned short* WTl   = WTh + 393216;          // 393216
  unsigned short* WoT   = WTl + 393216;          // 131072
  unsigned short* Qh    = WoT + 131072;          // 4194304
  unsigned short* Vh    = Qh + 4194304;          // 4194304
  unsigned short* Vl    = Vh + 4194304;          // 4194304
  unsigned short* Kt    = Vl + 4194304;          // 4194304
  unsigned short* Opart = Kt + 4194304;          // 8388608
  float2*         mlp   = (float2*)(Opart + 8388608);  // 65536 float2

  kwt<<<32, 256, 0, stream>>>(Wq, Wk, Wv, Wo, WTh, WTl, WoT);
  kprojf<<<dim3(64, 8), 256, 0, stream>>>(x, WTh, WTl, bq, bk, bv, Qh, Vh, Vl, Kt);
  kattn<<<dim3(8, 64, 2), 128, 0, stream>>>(Qh, Kt, Vh, Vl, Opart, mlp);
  koutm<<<256, 256, 0, stream>>>(Opart, mlp, WoT, bo, out);
}